// Round 9
// baseline (205.184 us; speedup 1.0000x reference)
//
#include <hip/hip_runtime.h>
#include <stdint.h>
#include <stddef.h>

typedef unsigned short ushort_t;
typedef __attribute__((ext_vector_type(8))) short short8;
typedef __attribute__((ext_vector_type(4))) short short4v;
typedef __attribute__((ext_vector_type(4))) float f32x4;

#define GL2LDS(gsrc, ldst) \
  __builtin_amdgcn_global_load_lds((const __attribute__((address_space(1))) void*)(gsrc), \
                                   (__attribute__((address_space(3))) void*)(ldst), 16, 0, 0)

__device__ __forceinline__ float bf2f(ushort_t u) {
  union { unsigned int i; float f; } v; v.i = ((unsigned int)u) << 16; return v.f;
}
__device__ __forceinline__ ushort_t f2bf(float f) {
  unsigned int u = __builtin_bit_cast(unsigned int, f);
  unsigned int r = (u + 0x7fffu + ((u >> 16) & 1u)) >> 16;
  return (ushort_t)r;
}

// ---------------------------------------------------------------------------
// K_front: fused preprocessing, dispatched by blockIdx:
//   [0,129)    pack e4w (+bias as tile 128) -> e4wP in MFMA-fragment order:
//              tile tg, frag fid=cf*4+ks, lane ln, elem q holds
//              M[tg*128 + (ks*4+(ln>>4))*8+q][cf*16+(ln&15)]
//              (M[c][o] = c<16384 ? e4w[c*128+o] : e4b[(c-16384)*128+o])
//   [129,145)  pack e2w -> w2h/w2l in MFMA-fragment order (hi/lo split)
//   [145,161)  pack e3w -> w3h/w3l in MFMA-fragment order (hi/lo split)
//   [161,673)  node MLP -> h_node bf16 [4096][128]
//   [673,705)  per-node edge counts: atomicAdd cnt[dst[e]]
// ---------------------------------------------------------------------------
__global__ void k_front(const float* __restrict__ e4w, const float* __restrict__ e4b,
                        ushort_t* __restrict__ e4wP,
                        const float* __restrict__ e2w, ushort_t* __restrict__ w2h,
                        ushort_t* __restrict__ w2l,
                        const float* __restrict__ e3w, ushort_t* __restrict__ w3h,
                        ushort_t* __restrict__ w3l,
                        const float* __restrict__ x, const float* __restrict__ p1w,
                        const float* __restrict__ p1b, const float* __restrict__ p2w,
                        const float* __restrict__ p2b, ushort_t* __restrict__ h_node,
                        const int* __restrict__ eidx, float* __restrict__ cnt) {
  __shared__ char smem[128 * 130 * 2];   // 33,280 B
  int bid = blockIdx.x, tid = threadIdx.x;

  if (bid < 129) {
    // ---- fragment-pack one K-tile of e4w (or the bias tile tg=128)
    int tg = bid;
    const float* src = (tg < 128) ? (e4w + (size_t)tg * 16384) : e4b;
    ushort_t (*t)[130] = (ushort_t(*)[130])smem;   // [k_local][o], +2 pad
#pragma unroll
    for (int it = 0; it < 16; ++it) {
      int idx = it * 256 + tid;                 // 0..4095 float4s
      int cl = idx >> 5, o4 = (idx & 31) * 4;
      float4 v = *(const float4*)(src + cl * 128 + o4);
      t[cl][o4 + 0] = f2bf(v.x);
      t[cl][o4 + 1] = f2bf(v.y);
      t[cl][o4 + 2] = f2bf(v.z);
      t[cl][o4 + 3] = f2bf(v.w);
    }
    __syncthreads();
    ushort_t* dst = e4wP + (size_t)tg * 16384;
#pragma unroll
    for (int it = 0; it < 8; ++it) {
      int fs = it * 256 + tid;                  // 0..2047 short8 slots
      int fid = fs >> 6, ln = fs & 63;
      int cf = fid >> 2, ks = fid & 3;
      int o = cf * 16 + (ln & 15);
      int k0 = (ks * 4 + (ln >> 4)) * 8;
      short8 p;
#pragma unroll
      for (int q = 0; q < 8; ++q) p[q] = (short)t[k0 + q][o];
      *(short8*)(dst + (size_t)fs * 8) = p;
    }
  } else if (bid < 145) {
    int id = (bid - 129) * 256 + tid;
    int cf = id >> 8, ks = (id >> 6) & 3, ln = id & 63;
    int n = cf * 16 + (ln & 15);
    int k0 = (ks * 4 + (ln >> 4)) * 8;
    short8 ph, pl;
#pragma unroll
    for (int q = 0; q < 8; ++q) {
      float v = e2w[(size_t)(k0 + q) * 256 + n];
      ushort_t hb = f2bf(v);
      ph[q] = (short)hb;
      pl[q] = (short)f2bf(v - bf2f(hb));
    }
    *(short8*)(w2h + (size_t)id * 8) = ph;
    *(short8*)(w2l + (size_t)id * 8) = pl;
  } else if (bid < 161) {
    int id = (bid - 145) * 256 + tid;
    int cf = id >> 9, ks = (id >> 6) & 7, ln = id & 63;
    int n = cf * 16 + (ln & 15);
    int k0 = (ks * 4 + (ln >> 4)) * 8;
    short8 ph, pl;
#pragma unroll
    for (int q = 0; q < 8; ++q) {
      float v = e3w[(size_t)(k0 + q) * 128 + n];
      ushort_t hb = f2bf(v);
      ph[q] = (short)hb;
      pl[q] = (short)f2bf(v - bf2f(hb));
    }
    *(short8*)(w3h + (size_t)id * 8) = ph;
    *(short8*)(w3l + (size_t)id * 8) = pl;
  } else if (bid < 673) {
    float (*xs)[12] = (float(*)[12])smem;
    float (*t1)[128] = (float(*)[128])(smem + 8 * 12 * 4);
    int n0 = (bid - 161) * 8;
    if (tid < 88) { int n = tid / 11, j = tid % 11; xs[n][j] = x[(size_t)(n0 + n) * 11 + j]; }
    __syncthreads();
    for (int it = 0; it < 4; ++it) {
      int p = it * 256 + tid;
      int n = p >> 7, o = p & 127;
      float a = p1b[o];
#pragma unroll
      for (int j = 0; j < 11; ++j) a += xs[n][j] * p1w[j * 128 + o];
      t1[n][o] = fmaxf(a, 0.f);
    }
    __syncthreads();
    {
      int o = tid & 127, nb = tid >> 7;
      float a0 = p2b[o], a1_ = a0, a2_ = a0, a3_ = a0;
      for (int k4 = 0; k4 < 32; ++k4) {
        float w0 = p2w[(k4 * 4 + 0) * 128 + o];
        float w1 = p2w[(k4 * 4 + 1) * 128 + o];
        float w2 = p2w[(k4 * 4 + 2) * 128 + o];
        float w3 = p2w[(k4 * 4 + 3) * 128 + o];
        float4 v0 = *(const float4*)&t1[nb + 0][k4 * 4];
        float4 v1 = *(const float4*)&t1[nb + 2][k4 * 4];
        float4 v2 = *(const float4*)&t1[nb + 4][k4 * 4];
        float4 v3 = *(const float4*)&t1[nb + 6][k4 * 4];
        a0 += v0.x * w0 + v0.y * w1 + v0.z * w2 + v0.w * w3;
        a1_ += v1.x * w0 + v1.y * w1 + v1.z * w2 + v1.w * w3;
        a2_ += v2.x * w0 + v2.y * w1 + v2.z * w2 + v2.w * w3;
        a3_ += v3.x * w0 + v3.y * w1 + v3.z * w2 + v3.w * w3;
      }
      h_node[(size_t)(n0 + nb + 0) * 128 + o] = f2bf(a0);
      h_node[(size_t)(n0 + nb + 2) * 128 + o] = f2bf(a1_);
      h_node[(size_t)(n0 + nb + 4) * 128 + o] = f2bf(a2_);
      h_node[(size_t)(n0 + nb + 6) * 128 + o] = f2bf(a3_);
    }
  } else {
    int e = (bid - 673) * 256 + tid;
    atomicAdd(&cnt[eidx[8192 + e]], 1.0f);
  }
}

// ---------------------------------------------------------------------------
// K2: edge MLP via split-bf16 MFMA (3-term), PREPACKED coalesced weights.
// 256 blocks x 512 thr, 32 edges/block. Outputs e3 fp32 [128 t][8192 e].
// ---------------------------------------------------------------------------
__global__ void k_mlp(const float* __restrict__ ea,
                      const float* __restrict__ e1w, const float* __restrict__ e1b,
                      const ushort_t* __restrict__ w2h, const ushort_t* __restrict__ w2l,
                      const float* __restrict__ e2b,
                      const ushort_t* __restrict__ w3h, const ushort_t* __restrict__ w3l,
                      const float* __restrict__ e3b,
                      float* __restrict__ e3Tf) {
  __shared__ float eas[32][6];
  __shared__ ushort_t a1h[32 * 136], a1l[32 * 136];
  __shared__ ushort_t a2h[32 * 264], a2l[32 * 264];
  __shared__ float a3t[128 * 40];

  int tid = threadIdx.x;
  int w = tid >> 6, ln = tid & 63, g = ln >> 4, l15 = ln & 15;
  int e0 = blockIdx.x * 32;

  if (tid < 160) { int n = tid / 5, j = tid % 5; eas[n][j] = ea[(size_t)(e0 + n) * 5 + j]; }
  __syncthreads();

  // L1: 5 -> 128, relu, split hi/lo
  {
    int n = tid >> 4, ob = (tid & 15) * 8;
    float acc1[8];
    float4 ba = *(const float4*)(e1b + ob);
    float4 bb = *(const float4*)(e1b + ob + 4);
    acc1[0] = ba.x; acc1[1] = ba.y; acc1[2] = ba.z; acc1[3] = ba.w;
    acc1[4] = bb.x; acc1[5] = bb.y; acc1[6] = bb.z; acc1[7] = bb.w;
#pragma unroll
    for (int j = 0; j < 5; ++j) {
      float aj = eas[n][j];
      float4 wa = *(const float4*)(e1w + j * 128 + ob);
      float4 wb = *(const float4*)(e1w + j * 128 + ob + 4);
      acc1[0] = fmaf(aj, wa.x, acc1[0]); acc1[1] = fmaf(aj, wa.y, acc1[1]);
      acc1[2] = fmaf(aj, wa.z, acc1[2]); acc1[3] = fmaf(aj, wa.w, acc1[3]);
      acc1[4] = fmaf(aj, wb.x, acc1[4]); acc1[5] = fmaf(aj, wb.y, acc1[5]);
      acc1[6] = fmaf(aj, wb.z, acc1[6]); acc1[7] = fmaf(aj, wb.w, acc1[7]);
    }
    short8 ph, pl;
#pragma unroll
    for (int q = 0; q < 8; ++q) {
      float v = fmaxf(acc1[q], 0.f);
      ushort_t hb = f2bf(v);
      ph[q] = (short)hb;
      pl[q] = (short)f2bf(v - bf2f(hb));
    }
    int addr = n * 136 + ob;
    *(short8*)(a1h + addr) = ph;
    *(short8*)(a1l + addr) = pl;
  }
  __syncthreads();

  // L2: 128 -> 256 (wave w: cols w*32..+31)
  {
    f32x4 acc2[2][2];
#pragma unroll
    for (int rf = 0; rf < 2; ++rf)
#pragma unroll
      for (int cf = 0; cf < 2; ++cf) acc2[rf][cf] = (f32x4){0.f, 0.f, 0.f, 0.f};
    short8 ah[2][4], al[2][4];
#pragma unroll
    for (int rf = 0; rf < 2; ++rf)
#pragma unroll
      for (int ks = 0; ks < 4; ++ks) {
        int row = rf * 16 + l15;
        int addr = row * 136 + (ks * 4 + g) * 8;
        ah[rf][ks] = *(const short8*)(a1h + addr);
        al[rf][ks] = *(const short8*)(a1l + addr);
      }
#pragma unroll
    for (int ks = 0; ks < 4; ++ks) {
#pragma unroll
      for (int cfi = 0; cfi < 2; ++cfi) {
        int cf = w * 2 + cfi;
        size_t poff = (size_t)(((cf * 4 + ks) << 6) + ln) * 8;
        short8 bh = *(const short8*)(w2h + poff);
        short8 bl = *(const short8*)(w2l + poff);
#pragma unroll
        for (int rf = 0; rf < 2; ++rf) {
          acc2[rf][cfi] = __builtin_amdgcn_mfma_f32_16x16x32_bf16(ah[rf][ks], bh, acc2[rf][cfi], 0, 0, 0);
          acc2[rf][cfi] = __builtin_amdgcn_mfma_f32_16x16x32_bf16(al[rf][ks], bh, acc2[rf][cfi], 0, 0, 0);
          acc2[rf][cfi] = __builtin_amdgcn_mfma_f32_16x16x32_bf16(ah[rf][ks], bl, acc2[rf][cfi], 0, 0, 0);
        }
      }
    }
#pragma unroll
    for (int rf = 0; rf < 2; ++rf)
#pragma unroll
      for (int cfi = 0; cfi < 2; ++cfi) {
        int col = (w * 2 + cfi) * 16 + l15;
        float b = e2b[col];
#pragma unroll
        for (int r2 = 0; r2 < 4; ++r2) {
          int row = rf * 16 + g * 4 + r2;
          float v = fmaxf(acc2[rf][cfi][r2] + b, 0.f);
          ushort_t hb = f2bf(v);
          int addr = row * 264 + col;
          a2h[addr] = hb;
          a2l[addr] = f2bf(v - bf2f(hb));
        }
      }
  }
  __syncthreads();

  // L3: 256 -> 128 (wave w: cols w*16..+15)
  {
    f32x4 acc3[2];
    acc3[0] = (f32x4){0.f, 0.f, 0.f, 0.f};
    acc3[1] = (f32x4){0.f, 0.f, 0.f, 0.f};
#pragma unroll
    for (int ks = 0; ks < 8; ++ks) {
      short8 a2hf[2], a2lf[2];
#pragma unroll
      for (int rf = 0; rf < 2; ++rf) {
        int row = rf * 16 + l15;
        int addr = row * 264 + (ks * 4 + g) * 8;
        a2hf[rf] = *(const short8*)(a2h + addr);
        a2lf[rf] = *(const short8*)(a2l + addr);
      }
      size_t poff = (size_t)(((w * 8 + ks) << 6) + ln) * 8;
      short8 bh = *(const short8*)(w3h + poff);
      short8 bl = *(const short8*)(w3l + poff);
#pragma unroll
      for (int rf = 0; rf < 2; ++rf) {
        acc3[rf] = __builtin_amdgcn_mfma_f32_16x16x32_bf16(a2hf[rf], bh, acc3[rf], 0, 0, 0);
        acc3[rf] = __builtin_amdgcn_mfma_f32_16x16x32_bf16(a2lf[rf], bh, acc3[rf], 0, 0, 0);
        acc3[rf] = __builtin_amdgcn_mfma_f32_16x16x32_bf16(a2hf[rf], bl, acc3[rf], 0, 0, 0);
      }
    }
    int col = w * 16 + l15;
    float b = e3b[col];
#pragma unroll
    for (int rf = 0; rf < 2; ++rf)
#pragma unroll
      for (int r2 = 0; r2 < 4; ++r2) {
        int row = rf * 16 + g * 4 + r2;
        float v = fmaxf(acc3[rf][r2] + b, 0.f);
        a3t[col * 40 + row] = v;
      }
  }
  __syncthreads();

  {
    int o = tid >> 2, eq = (tid & 3) * 8;
    float4 q0 = *(const float4*)(a3t + o * 40 + eq);
    float4 q1 = *(const float4*)(a3t + o * 40 + eq + 4);
    *(float4*)(e3Tf + (size_t)o * 8192 + e0 + eq) = q0;
    *(float4*)(e3Tf + (size_t)o * 8192 + e0 + eq + 4) = q1;
  }
}

// ---------------------------------------------------------------------------
// K3: fused GEMM + scatter. 256 blocks = 64 mtiles x 4 splits, 512 thr =
// 8 waves; wave w owns cols w*16..+15, ALL 128 rows (A in afr[8][4] regs).
// B now FRAGMENT-PACKED (e4wP): each wave B-load = one contiguous 1KB
// transaction (was 16 scattered 64B lines at 33KB stride — r8's latency
// bottleneck). Depth-2 register prefetch via 3 named buffers (const-indexed,
// rule #20). Barrier-free K-loop; atomic scatter epilogue (reduce fused).
// launch_bounds(512,1): do NOT cap VGPR (r7 lesson: ILP > forced TLP).
// ---------------------------------------------------------------------------
__launch_bounds__(512, 1)
__global__ void k_gemm(const ushort_t* __restrict__ h_node, const int* __restrict__ eidx,
                       const float* __restrict__ e3Tf,
                       const ushort_t* __restrict__ e4wP, float* __restrict__ agg) {
  __shared__ ushort_t bufA[16384];   // 32KB A tile (swizzled)
  __shared__ float e3s[32 * 128];    // 16KB f32 e3 slice [tile][edge]
  __shared__ int dsts[128];          // dst node per edge row

  int tid = threadIdx.x;
  int w = tid >> 6, ln = tid & 63;
  int g = ln >> 4, l15 = ln & 15;
  int bid = blockIdx.x;
  int mt = bid >> 2, s = bid & 3;
  int e0 = mt * 128;
  int t0 = s * 32;
  int nt = (s == 3) ? 33 : 32;

  // ---- prologue: gather A rows (h_node[src[e]]) + e3 slice + dst indices
  if (tid < 128) dsts[tid] = eidx[8192 + e0 + tid];
  {
#pragma unroll
    for (int it = 0; it < 4; ++it) {
      int chunk = it * 512 + tid;
      int r = chunk >> 4;
      int Gt = (chunk & 15) ^ (r & 15);
      int se = eidx[e0 + r];
      GL2LDS(h_node + (size_t)se * 128 + Gt * 8, (char*)&bufA[0] + (it * 512 + w * 64) * 16);
    }
#pragma unroll
    for (int it = 0; it < 2; ++it) {
      int chunk = it * 512 + tid;
      int tl = chunk >> 5, cc = chunk & 31;
      GL2LDS(e3Tf + (size_t)(t0 + tl) * 8192 + e0 + cc * 4,
             (char*)&e3s[0] + (it * 512 + w * 64) * 16);
    }
  }
  asm volatile("s_waitcnt vmcnt(0)" ::: "memory");
  __builtin_amdgcn_s_barrier();
  asm volatile("" ::: "memory");

  // ---- A fragments: afr[rf][ks], live across all tiles
  short8 afr[8][4];
#pragma unroll
  for (int rf = 0; rf < 8; ++rf)
#pragma unroll
    for (int ks = 0; ks < 4; ++ks) {
      int row = rf * 16 + l15;
      int gr = (ks * 4 + g) ^ (row & 15);
      afr[rf][ks] = *(const short8*)((const char*)&bufA[0] + row * 256 + gr * 16);
    }

  f32x4 acc[8];
#pragma unroll
  for (int rf = 0; rf < 8; ++rf) acc[rf] = (f32x4){0.f, 0.f, 0.f, 0.f};

  const f32x4 zero4 = {0.f, 0.f, 0.f, 0.f};
  int nrow = w * 16 + l15;  // this wave-lane's output column

  // B: fragment-packed, contiguous per wave. frag(tg, cf=w, ks), lane ln.
  const size_t TSTR = 32 * 64 * 8;  // 16384 elems per K-tile
  const ushort_t* bp = e4wP + (((size_t)t0 * 32 + w * 4) * 64 + ln) * 8;
  short8 b0[4], b1[4], b2[4];
#pragma unroll
  for (int ks = 0; ks < 4; ++ks) b0[ks] = *(const short8*)(bp + ks * 512);
  bp += TSTR;
#pragma unroll
  for (int ks = 0; ks < 4; ++ks) b1[ks] = *(const short8*)(bp + ks * 512);
  bp += TSTR;

  for (int tl = 0; tl < nt; ++tl) {
    int tg = t0 + tl;

    // depth-2 prefetch: tile tl+2 issues while tiles tl (regs) and tl+1 (flight)
    if (tl + 2 < nt) {
#pragma unroll
      for (int ks = 0; ks < 4; ++ks) b2[ks] = *(const short8*)(bp + ks * 512);
      bp += TSTR;
    }

    f32x4 part[8];
#pragma unroll
    for (int rf = 0; rf < 8; ++rf)
      part[rf] = __builtin_amdgcn_mfma_f32_16x16x32_bf16(afr[rf][0], b0[0], zero4, 0, 0, 0);
#pragma unroll
    for (int ks = 1; ks < 4; ++ks)
#pragma unroll
      for (int rf = 0; rf < 8; ++rf)
        part[rf] = __builtin_amdgcn_mfma_f32_16x16x32_bf16(afr[rf][ks], b0[ks], part[rf], 0, 0, 0);

    if (tg < 128) {
#pragma unroll
      for (int rf = 0; rf < 8; ++rf) {
        float4 ev = *(const float4*)&e3s[tl * 128 + rf * 16 + g * 4];
        acc[rf][0] = fmaf(ev.x, part[rf][0], acc[rf][0]);
        acc[rf][1] = fmaf(ev.y, part[rf][1], acc[rf][1]);
        acc[rf][2] = fmaf(ev.z, part[rf][2], acc[rf][2]);
        acc[rf][3] = fmaf(ev.w, part[rf][3], acc[rf][3]);
      }
    } else {
#pragma unroll
      for (int rf = 0; rf < 8; ++rf)
#pragma unroll
        for (int r2 = 0; r2 < 4; ++r2) acc[rf][r2] += part[rf][r2];
    }

    // rotate buffers (const indices -> stays in registers)
#pragma unroll
    for (int ks = 0; ks < 4; ++ks) { b0[ks] = b1[ks]; b1[ks] = b2[ks]; }
  }

  // epilogue: scatter-add into agg[dst] (absorbs k_reduce)
#pragma unroll
  for (int rf = 0; rf < 8; ++rf)
#pragma unroll
    for (int r2 = 0; r2 < 4; ++r2) {
      int row = rf * 16 + g * 4 + r2;
      int d = dsts[row];
      atomicAdd(&agg[(size_t)d * 128 + nrow], acc[rf][r2]);
    }
}

// ---------------------------------------------------------------------------
// K5: per-graph pooling
// ---------------------------------------------------------------------------
__device__ __forceinline__ int lbound(const int* a, int n, int v) {
  int lo = 0, hi = n;
  while (lo < hi) { int m = (lo + hi) >> 1; if (a[m] < v) lo = m + 1; else hi = m; }
  return lo;
}

__global__ void k_pool(const float* __restrict__ agg, const float* __restrict__ cnt,
                       const int* __restrict__ batch, float* __restrict__ out) {
  int gph = blockIdx.x, o = threadIdx.x;
  int lo = lbound(batch, 4096, gph);
  int hi = lbound(batch, 4096, gph + 1);
  float a = 0.f;
  for (int n = lo; n < hi; ++n) a += agg[(size_t)n * 128 + o] / fmaxf(cnt[n], 1.0f);
  out[(size_t)gph * 128 + o] = a;
}

// ---------------------------------------------------------------------------
extern "C" void kernel_launch(void* const* d_in, const int* in_sizes, int n_in,
                              void* d_out, int out_size, void* d_ws, size_t ws_size,
                              hipStream_t stream) {
  (void)in_sizes; (void)n_in; (void)out_size; (void)ws_size;
  const float* x   = (const float*)d_in[0];
  const float* ea  = (const float*)d_in[1];
  const int*   ei  = (const int*)d_in[2];
  const int*   bat = (const int*)d_in[3];
  const float* p1w = (const float*)d_in[4];  const float* p1b = (const float*)d_in[5];
  const float* p2w = (const float*)d_in[6];  const float* p2b = (const float*)d_in[7];
  const float* e1w = (const float*)d_in[8];  const float* e1b = (const float*)d_in[9];
  const float* e2w = (const float*)d_in[10]; const float* e2b = (const float*)d_in[11];
  const float* e3w = (const float*)d_in[12]; const float* e3b = (const float*)d_in[13];
  const float* e4w = (const float*)d_in[14]; const float* e4b = (const float*)d_in[15];

  char* ws = (char*)d_ws;
  ushort_t* e4wP   = (ushort_t*)(ws + 0);          // 129 x 16384 bf16 = 4,227,072
  ushort_t* h_node = (ushort_t*)(ws + 4227072);    // 4096 x 128 bf16 = 1,048,576
  float*    e3Tf   = (float*)(ws + 5275648);       // 128 x 8192 f32 = 4,194,304
  float*    agg    = (float*)(ws + 9469952);       // 4096 x 128 f32 = 2,097,152
  float*    cnt    = (float*)(ws + 11567104);      // 4096 f32 = 16,384
  ushort_t* w2h    = (ushort_t*)(ws + 11583488);   // 65,536 (packed fragments)
  ushort_t* w2l    = (ushort_t*)(ws + 11649024);
  ushort_t* w3h    = (ushort_t*)(ws + 11714560);
  ushort_t* w3l    = (ushort_t*)(ws + 11780096);

  hipMemsetAsync(ws + 9469952, 0, 2097152 + 16384, stream);

  k_front <<<705,  256, 0, stream>>>(e4w, e4b, e4wP, e2w, w2h, w2l, e3w, w3h, w3l,
                                     x, p1w, p1b, p2w, p2b, h_node, ei, cnt);
  k_mlp   <<<256,  512, 0, stream>>>(ea, e1w, e1b, w2h, w2l, e2b,
                                     w3h, w3l, e3b, e3Tf);
  k_gemm  <<<256,  512, 0, stream>>>(h_node, ei, e3Tf, e4wP, agg);
  k_pool  <<<64,   128, 0, stream>>>(agg, cnt, bat, (float*)d_out);
}

// Round 12
// 177.077 us; speedup vs baseline: 1.1587x; 1.1587x over previous
//
#include <hip/hip_runtime.h>
#include <stdint.h>
#include <stddef.h>

typedef unsigned short ushort_t;
typedef __attribute__((ext_vector_type(8))) short short8;
typedef __attribute__((ext_vector_type(4))) short short4v;
typedef __attribute__((ext_vector_type(4))) float f32x4;

#define GL2LDS(gsrc, ldst) \
  __builtin_amdgcn_global_load_lds((const __attribute__((address_space(1))) void*)(gsrc), \
                                   (__attribute__((address_space(3))) void*)(ldst), 16, 0, 0)

__device__ __forceinline__ float bf2f(ushort_t u) {
  union { unsigned int i; float f; } v; v.i = ((unsigned int)u) << 16; return v.f;
}
__device__ __forceinline__ ushort_t f2bf(float f) {
  unsigned int u = __builtin_bit_cast(unsigned int, f);
  unsigned int r = (u + 0x7fffu + ((u >> 16) & 1u)) >> 16;
  return (ushort_t)r;
}

// ---------------------------------------------------------------------------
// K_front: fused preprocessing, dispatched by blockIdx:
//   [0,129)    pack e4w (+bias as tile 128) -> e4wP in MFMA-fragment order
//   [129,145)  pack e2w -> w2h/w2l (hi/lo split, fragment order)
//   [145,161)  pack e3w -> w3h/w3l (hi/lo split, fragment order)
//   [161,673)  node MLP -> h_node bf16 [4096][128]
//   [673,705)  per-node edge counts into cnt
// ---------------------------------------------------------------------------
__global__ void k_front(const float* __restrict__ e4w, const float* __restrict__ e4b,
                        ushort_t* __restrict__ e4wP,
                        const float* __restrict__ e2w, ushort_t* __restrict__ w2h,
                        ushort_t* __restrict__ w2l,
                        const float* __restrict__ e3w, ushort_t* __restrict__ w3h,
                        ushort_t* __restrict__ w3l,
                        const float* __restrict__ x, const float* __restrict__ p1w,
                        const float* __restrict__ p1b, const float* __restrict__ p2w,
                        const float* __restrict__ p2b, ushort_t* __restrict__ h_node,
                        const int* __restrict__ eidx, float* __restrict__ cnt) {
  __shared__ char smem[128 * 130 * 2];   // 33,280 B
  int bid = blockIdx.x, tid = threadIdx.x;

  if (bid < 129) {
    int tg = bid;
    const float* src = (tg < 128) ? (e4w + (size_t)tg * 16384) : e4b;
    ushort_t (*t)[130] = (ushort_t(*)[130])smem;
#pragma unroll
    for (int it = 0; it < 16; ++it) {
      int idx = it * 256 + tid;
      int cl = idx >> 5, o4 = (idx & 31) * 4;
      float4 v = *(const float4*)(src + cl * 128 + o4);
      t[cl][o4 + 0] = f2bf(v.x);
      t[cl][o4 + 1] = f2bf(v.y);
      t[cl][o4 + 2] = f2bf(v.z);
      t[cl][o4 + 3] = f2bf(v.w);
    }
    __syncthreads();
    ushort_t* dst = e4wP + (size_t)tg * 16384;
#pragma unroll
    for (int it = 0; it < 8; ++it) {
      int fs = it * 256 + tid;
      int fid = fs >> 6, ln = fs & 63;
      int cf = fid >> 2, ks = fid & 3;
      int o = cf * 16 + (ln & 15);
      int k0 = (ks * 4 + (ln >> 4)) * 8;
      short8 p;
#pragma unroll
      for (int q = 0; q < 8; ++q) p[q] = (short)t[k0 + q][o];
      *(short8*)(dst + (size_t)fs * 8) = p;
    }
  } else if (bid < 145) {
    int id = (bid - 129) * 256 + tid;
    int cf = id >> 8, ks = (id >> 6) & 3, ln = id & 63;
    int n = cf * 16 + (ln & 15);
    int k0 = (ks * 4 + (ln >> 4)) * 8;
    short8 ph, pl;
#pragma unroll
    for (int q = 0; q < 8; ++q) {
      float v = e2w[(size_t)(k0 + q) * 256 + n];
      ushort_t hb = f2bf(v);
      ph[q] = (short)hb;
      pl[q] = (short)f2bf(v - bf2f(hb));
    }
    *(short8*)(w2h + (size_t)id * 8) = ph;
    *(short8*)(w2l + (size_t)id * 8) = pl;
  } else if (bid < 161) {
    int id = (bid - 145) * 256 + tid;
    int cf = id >> 9, ks = (id >> 6) & 7, ln = id & 63;
    int n = cf * 16 + (ln & 15);
    int k0 = (ks * 4 + (ln >> 4)) * 8;
    short8 ph, pl;
#pragma unroll
    for (int q = 0; q < 8; ++q) {
      float v = e3w[(size_t)(k0 + q) * 128 + n];
      ushort_t hb = f2bf(v);
      ph[q] = (short)hb;
      pl[q] = (short)f2bf(v - bf2f(hb));
    }
    *(short8*)(w3h + (size_t)id * 8) = ph;
    *(short8*)(w3l + (size_t)id * 8) = pl;
  } else if (bid < 673) {
    float (*xs)[12] = (float(*)[12])smem;
    float (*t1)[128] = (float(*)[128])(smem + 8 * 12 * 4);
    int n0 = (bid - 161) * 8;
    if (tid < 88) { int n = tid / 11, j = tid % 11; xs[n][j] = x[(size_t)(n0 + n) * 11 + j]; }
    __syncthreads();
    for (int it = 0; it < 4; ++it) {
      int p = it * 256 + tid;
      int n = p >> 7, o = p & 127;
      float a = p1b[o];
#pragma unroll
      for (int j = 0; j < 11; ++j) a += xs[n][j] * p1w[j * 128 + o];
      t1[n][o] = fmaxf(a, 0.f);
    }
    __syncthreads();
    {
      int o = tid & 127, nb = tid >> 7;
      float a0 = p2b[o], a1_ = a0, a2_ = a0, a3_ = a0;
      for (int k4 = 0; k4 < 32; ++k4) {
        float w0 = p2w[(k4 * 4 + 0) * 128 + o];
        float w1 = p2w[(k4 * 4 + 1) * 128 + o];
        float w2 = p2w[(k4 * 4 + 2) * 128 + o];
        float w3 = p2w[(k4 * 4 + 3) * 128 + o];
        float4 v0 = *(const float4*)&t1[nb + 0][k4 * 4];
        float4 v1 = *(const float4*)&t1[nb + 2][k4 * 4];
        float4 v2 = *(const float4*)&t1[nb + 4][k4 * 4];
        float4 v3 = *(const float4*)&t1[nb + 6][k4 * 4];
        a0 += v0.x * w0 + v0.y * w1 + v0.z * w2 + v0.w * w3;
        a1_ += v1.x * w0 + v1.y * w1 + v1.z * w2 + v1.w * w3;
        a2_ += v2.x * w0 + v2.y * w1 + v2.z * w2 + v2.w * w3;
        a3_ += v3.x * w0 + v3.y * w1 + v3.z * w2 + v3.w * w3;
      }
      h_node[(size_t)(n0 + nb + 0) * 128 + o] = f2bf(a0);
      h_node[(size_t)(n0 + nb + 2) * 128 + o] = f2bf(a1_);
      h_node[(size_t)(n0 + nb + 4) * 128 + o] = f2bf(a2_);
      h_node[(size_t)(n0 + nb + 6) * 128 + o] = f2bf(a3_);
    }
  } else {
    int e = (bid - 673) * 256 + tid;
    atomicAdd(&cnt[eidx[8192 + e]], 1.0f);
  }
}

// ---------------------------------------------------------------------------
// K2: edge MLP via split-bf16 MFMA (3-term), PREPACKED coalesced weights.
// ---------------------------------------------------------------------------
__global__ void k_mlp(const float* __restrict__ ea,
                      const float* __restrict__ e1w, const float* __restrict__ e1b,
                      const ushort_t* __restrict__ w2h, const ushort_t* __restrict__ w2l,
                      const float* __restrict__ e2b,
                      const ushort_t* __restrict__ w3h, const ushort_t* __restrict__ w3l,
                      const float* __restrict__ e3b,
                      float* __restrict__ e3Tf) {
  __shared__ float eas[32][6];
  __shared__ ushort_t a1h[32 * 136], a1l[32 * 136];
  __shared__ ushort_t a2h[32 * 264], a2l[32 * 264];
  __shared__ float a3t[128 * 40];

  int tid = threadIdx.x;
  int w = tid >> 6, ln = tid & 63, g = ln >> 4, l15 = ln & 15;
  int e0 = blockIdx.x * 32;

  if (tid < 160) { int n = tid / 5, j = tid % 5; eas[n][j] = ea[(size_t)(e0 + n) * 5 + j]; }
  __syncthreads();

  // L1: 5 -> 128, relu, split hi/lo
  {
    int n = tid >> 4, ob = (tid & 15) * 8;
    float acc1[8];
    float4 ba = *(const float4*)(e1b + ob);
    float4 bb = *(const float4*)(e1b + ob + 4);
    acc1[0] = ba.x; acc1[1] = ba.y; acc1[2] = ba.z; acc1[3] = ba.w;
    acc1[4] = bb.x; acc1[5] = bb.y; acc1[6] = bb.z; acc1[7] = bb.w;
#pragma unroll
    for (int j = 0; j < 5; ++j) {
      float aj = eas[n][j];
      float4 wa = *(const float4*)(e1w + j * 128 + ob);
      float4 wb = *(const float4*)(e1w + j * 128 + ob + 4);
      acc1[0] = fmaf(aj, wa.x, acc1[0]); acc1[1] = fmaf(aj, wa.y, acc1[1]);
      acc1[2] = fmaf(aj, wa.z, acc1[2]); acc1[3] = fmaf(aj, wa.w, acc1[3]);
      acc1[4] = fmaf(aj, wb.x, acc1[4]); acc1[5] = fmaf(aj, wb.y, acc1[5]);
      acc1[6] = fmaf(aj, wb.z, acc1[6]); acc1[7] = fmaf(aj, wb.w, acc1[7]);
    }
    short8 ph, pl;
#pragma unroll
    for (int q = 0; q < 8; ++q) {
      float v = fmaxf(acc1[q], 0.f);
      ushort_t hb = f2bf(v);
      ph[q] = (short)hb;
      pl[q] = (short)f2bf(v - bf2f(hb));
    }
    int addr = n * 136 + ob;
    *(short8*)(a1h + addr) = ph;
    *(short8*)(a1l + addr) = pl;
  }
  __syncthreads();

  // L2: 128 -> 256 (wave w: cols w*32..+31)
  {
    f32x4 acc2[2][2];
#pragma unroll
    for (int rf = 0; rf < 2; ++rf)
#pragma unroll
      for (int cf = 0; cf < 2; ++cf) acc2[rf][cf] = (f32x4){0.f, 0.f, 0.f, 0.f};
    short8 ah[2][4], al[2][4];
#pragma unroll
    for (int rf = 0; rf < 2; ++rf)
#pragma unroll
      for (int ks = 0; ks < 4; ++ks) {
        int row = rf * 16 + l15;
        int addr = row * 136 + (ks * 4 + g) * 8;
        ah[rf][ks] = *(const short8*)(a1h + addr);
        al[rf][ks] = *(const short8*)(a1l + addr);
      }
#pragma unroll
    for (int ks = 0; ks < 4; ++ks) {
#pragma unroll
      for (int cfi = 0; cfi < 2; ++cfi) {
        int cf = w * 2 + cfi;
        size_t poff = (size_t)(((cf * 4 + ks) << 6) + ln) * 8;
        short8 bh = *(const short8*)(w2h + poff);
        short8 bl = *(const short8*)(w2l + poff);
#pragma unroll
        for (int rf = 0; rf < 2; ++rf) {
          acc2[rf][cfi] = __builtin_amdgcn_mfma_f32_16x16x32_bf16(ah[rf][ks], bh, acc2[rf][cfi], 0, 0, 0);
          acc2[rf][cfi] = __builtin_amdgcn_mfma_f32_16x16x32_bf16(al[rf][ks], bh, acc2[rf][cfi], 0, 0, 0);
          acc2[rf][cfi] = __builtin_amdgcn_mfma_f32_16x16x32_bf16(ah[rf][ks], bl, acc2[rf][cfi], 0, 0, 0);
        }
      }
    }
#pragma unroll
    for (int rf = 0; rf < 2; ++rf)
#pragma unroll
      for (int cfi = 0; cfi < 2; ++cfi) {
        int col = (w * 2 + cfi) * 16 + l15;
        float b = e2b[col];
#pragma unroll
        for (int r2 = 0; r2 < 4; ++r2) {
          int row = rf * 16 + g * 4 + r2;
          float v = fmaxf(acc2[rf][cfi][r2] + b, 0.f);
          ushort_t hb = f2bf(v);
          int addr = row * 264 + col;
          a2h[addr] = hb;
          a2l[addr] = f2bf(v - bf2f(hb));
        }
      }
  }
  __syncthreads();

  // L3: 256 -> 128 (wave w: cols w*16..+15)
  {
    f32x4 acc3[2];
    acc3[0] = (f32x4){0.f, 0.f, 0.f, 0.f};
    acc3[1] = (f32x4){0.f, 0.f, 0.f, 0.f};
#pragma unroll
    for (int ks = 0; ks < 8; ++ks) {
      short8 a2hf[2], a2lf[2];
#pragma unroll
      for (int rf = 0; rf < 2; ++rf) {
        int row = rf * 16 + l15;
        int addr = row * 264 + (ks * 4 + g) * 8;
        a2hf[rf] = *(const short8*)(a2h + addr);
        a2lf[rf] = *(const short8*)(a2l + addr);
      }
      size_t poff = (size_t)(((w * 8 + ks) << 6) + ln) * 8;
      short8 bh = *(const short8*)(w3h + poff);
      short8 bl = *(const short8*)(w3l + poff);
#pragma unroll
      for (int rf = 0; rf < 2; ++rf) {
        acc3[rf] = __builtin_amdgcn_mfma_f32_16x16x32_bf16(a2hf[rf], bh, acc3[rf], 0, 0, 0);
        acc3[rf] = __builtin_amdgcn_mfma_f32_16x16x32_bf16(a2lf[rf], bh, acc3[rf], 0, 0, 0);
        acc3[rf] = __builtin_amdgcn_mfma_f32_16x16x32_bf16(a2hf[rf], bl, acc3[rf], 0, 0, 0);
      }
    }
    int col = w * 16 + l15;
    float b = e3b[col];
#pragma unroll
    for (int rf = 0; rf < 2; ++rf)
#pragma unroll
      for (int r2 = 0; r2 < 4; ++r2) {
        int row = rf * 16 + g * 4 + r2;
        float v = fmaxf(acc3[rf][r2] + b, 0.f);
        a3t[col * 40 + row] = v;
      }
  }
  __syncthreads();

  {
    int o = tid >> 2, eq = (tid & 3) * 8;
    float4 q0 = *(const float4*)(a3t + o * 40 + eq);
    float4 q1 = *(const float4*)(a3t + o * 40 + eq + 4);
    *(float4*)(e3Tf + (size_t)o * 8192 + e0 + eq) = q0;
    *(float4*)(e3Tf + (size_t)o * 8192 + e0 + eq + 4) = q1;
  }
}

// ---------------------------------------------------------------------------
// K3: fused GEMM + scatter. 256 blocks = 64 mtiles x 4 splits, 512 thr =
// 8 waves; wave w owns cols w*16..+15, ALL 128 rows (A in afr[8][4] regs).
// B fragment-packed (1KB contiguous per wave-load). PING-PONG unroll-by-2:
// compute b0 -> reload b0<-tl+2 -> compute b1 -> reload b1<-tl+3. Two
// buffers, zero rotation moves, VGPR ~116 (r9's depth-2 third buffer hit
// the 128 cap and SPILLED: WRITE_SIZE 16.4->23.6MB — reverted).
// launch_bounds(512,1): do NOT cap VGPR (r7 lesson).
// ---------------------------------------------------------------------------
__launch_bounds__(512, 1)
__global__ void k_gemm(const ushort_t* __restrict__ h_node, const int* __restrict__ eidx,
                       const float* __restrict__ e3Tf,
                       const ushort_t* __restrict__ e4wP, float* __restrict__ agg) {
  __shared__ ushort_t bufA[16384];   // 32KB A tile (swizzled)
  __shared__ float e3s[32 * 128];    // 16KB f32 e3 slice [tile][edge]
  __shared__ int dsts[128];

  int tid = threadIdx.x;
  int w = tid >> 6, ln = tid & 63;
  int g = ln >> 4, l15 = ln & 15;
  int bid = blockIdx.x;
  int mt = bid >> 2, s = bid & 3;
  int e0 = mt * 128;
  int t0 = s * 32;
  int nt = (s == 3) ? 33 : 32;

  // ---- prologue: gather A rows + e3 slice + dst indices
  if (tid < 128) dsts[tid] = eidx[8192 + e0 + tid];
  {
#pragma unroll
    for (int it = 0; it < 4; ++it) {
      int chunk = it * 512 + tid;
      int r = chunk >> 4;
      int Gt = (chunk & 15) ^ (r & 15);
      int se = eidx[e0 + r];
      GL2LDS(h_node + (size_t)se * 128 + Gt * 8, (char*)&bufA[0] + (it * 512 + w * 64) * 16);
    }
#pragma unroll
    for (int it = 0; it < 2; ++it) {
      int chunk = it * 512 + tid;
      int tl = chunk >> 5, cc = chunk & 31;
      GL2LDS(e3Tf + (size_t)(t0 + tl) * 8192 + e0 + cc * 4,
             (char*)&e3s[0] + (it * 512 + w * 64) * 16);
    }
  }
  asm volatile("s_waitcnt vmcnt(0)" ::: "memory");
  __builtin_amdgcn_s_barrier();
  asm volatile("" ::: "memory");

  // ---- A fragments, live across all tiles
  short8 afr[8][4];
#pragma unroll
  for (int rf = 0; rf < 8; ++rf)
#pragma unroll
    for (int ks = 0; ks < 4; ++ks) {
      int row = rf * 16 + l15;
      int gr = (ks * 4 + g) ^ (row & 15);
      afr[rf][ks] = *(const short8*)((const char*)&bufA[0] + row * 256 + gr * 16);
    }

  f32x4 acc[8];
#pragma unroll
  for (int rf = 0; rf < 8; ++rf) acc[rf] = (f32x4){0.f, 0.f, 0.f, 0.f};

  const f32x4 zero4 = {0.f, 0.f, 0.f, 0.f};
  int nrow = w * 16 + l15;

  // B: fragment-packed, contiguous per wave.
  const size_t TSTR = 16384;  // elems per K-tile
  const ushort_t* bp = e4wP + (((size_t)t0 * 32 + w * 4) * 64 + ln) * 8;
  short8 b0[4], b1[4];
#pragma unroll
  for (int ks = 0; ks < 4; ++ks) b0[ks] = *(const short8*)(bp + ks * 512);
#pragma unroll
  for (int ks = 0; ks < 4; ++ks) b1[ks] = *(const short8*)(bp + TSTR + ks * 512);

  auto doTile = [&](const short8 (&bf)[4], int tl) {
    int tg = t0 + tl;
    f32x4 part[8];
#pragma unroll
    for (int rf = 0; rf < 8; ++rf)
      part[rf] = __builtin_amdgcn_mfma_f32_16x16x32_bf16(afr[rf][0], bf[0], zero4, 0, 0, 0);
#pragma unroll
    for (int ks = 1; ks < 4; ++ks)
#pragma unroll
      for (int rf = 0; rf < 8; ++rf)
        part[rf] = __builtin_amdgcn_mfma_f32_16x16x32_bf16(afr[rf][ks], bf[ks], part[rf], 0, 0, 0);
    if (tg < 128) {
#pragma unroll
      for (int rf = 0; rf < 8; ++rf) {
        float4 ev = *(const float4*)&e3s[tl * 128 + rf * 16 + g * 4];
        acc[rf][0] = fmaf(ev.x, part[rf][0], acc[rf][0]);
        acc[rf][1] = fmaf(ev.y, part[rf][1], acc[rf][1]);
        acc[rf][2] = fmaf(ev.z, part[rf][2], acc[rf][2]);
        acc[rf][3] = fmaf(ev.w, part[rf][3], acc[rf][3]);
      }
    } else {
#pragma unroll
      for (int rf = 0; rf < 8; ++rf)
#pragma unroll
        for (int r2 = 0; r2 < 4; ++r2) acc[rf][r2] += part[rf][r2];
    }
  };

  for (int tl = 0; tl < nt; tl += 2) {
    // even tile from b0
    doTile(b0, tl);
    if (tl + 2 < nt) {
      const ushort_t* bq = bp + (size_t)(tl + 2) * TSTR;
#pragma unroll
      for (int ks = 0; ks < 4; ++ks) b0[ks] = *(const short8*)(bq + ks * 512);
    }
    // odd tile from b1
    if (tl + 1 < nt) {
      doTile(b1, tl + 1);
      if (tl + 3 < nt) {
        const ushort_t* bq = bp + (size_t)(tl + 3) * TSTR;
#pragma unroll
        for (int ks = 0; ks < 4; ++ks) b1[ks] = *(const short8*)(bq + ks * 512);
      }
    }
  }

  // epilogue: scatter-add into agg[dst]
#pragma unroll
  for (int rf = 0; rf < 8; ++rf)
#pragma unroll
    for (int r2 = 0; r2 < 4; ++r2) {
      int row = rf * 16 + g * 4 + r2;
      int d = dsts[row];
      atomicAdd(&agg[(size_t)d * 128 + nrow], acc[rf][r2]);
    }
}

// ---------------------------------------------------------------------------
// K5: per-graph pooling
// ---------------------------------------------------------------------------
__device__ __forceinline__ int lbound(const int* a, int n, int v) {
  int lo = 0, hi = n;
  while (lo < hi) { int m = (lo + hi) >> 1; if (a[m] < v) lo = m + 1; else hi = m; }
  return lo;
}

__global__ void k_pool(const float* __restrict__ agg, const float* __restrict__ cnt,
                       const int* __restrict__ batch, float* __restrict__ out) {
  int gph = blockIdx.x, o = threadIdx.x;
  int lo = lbound(batch, 4096, gph);
  int hi = lbound(batch, 4096, gph + 1);
  float a = 0.f;
  for (int n = lo; n < hi; ++n) a += agg[(size_t)n * 128 + o] / fmaxf(cnt[n], 1.0f);
  out[(size_t)gph * 128 + o] = a;
}

// ---------------------------------------------------------------------------
extern "C" void kernel_launch(void* const* d_in, const int* in_sizes, int n_in,
                              void* d_out, int out_size, void* d_ws, size_t ws_size,
                              hipStream_t stream) {
  (void)in_sizes; (void)n_in; (void)out_size; (void)ws_size;
  const float* x   = (const float*)d_in[0];
  const float* ea  = (const float*)d_in[1];
  const int*   ei  = (const int*)d_in[2];
  const int*   bat = (const int*)d_in[3];
  const float* p1w = (const float*)d_in[4];  const float* p1b = (const float*)d_in[5];
  const float* p2w = (const float*)d_in[6];  const float* p2b = (const float*)d_in[7];
  const float* e1w = (const float*)d_in[8];  const float* e1b = (const float*)d_in[9];
  const float* e2w = (const float*)d_in[10]; const float* e2b = (const float*)d_in[11];
  const float* e3w = (const float*)d_in[12]; const float* e3b = (const float*)d_in[13];
  const float* e4w = (const float*)d_in[14]; const float* e4b = (const float*)d_in[15];

  char* ws = (char*)d_ws;
  ushort_t* e4wP   = (ushort_t*)(ws + 0);          // 129 x 16384 bf16 = 4,227,072
  ushort_t* h_node = (ushort_t*)(ws + 4227072);    // 4096 x 128 bf16 = 1,048,576
  float*    e3Tf   = (float*)(ws + 5275648);       // 128 x 8192 f32 = 4,194,304
  float*    agg    = (float*)(ws + 9469952);       // 4096 x 128 f32 = 2,097,152
  float*    cnt    = (float*)(ws + 11567104);      // 4096 f32 = 16,384
  ushort_t* w2h    = (ushort_t*)(ws + 11583488);   // 65,536 (packed fragments)
  ushort_t* w2l    = (ushort_t*)(ws + 11649024);
  ushort_t* w3h    = (ushort_t*)(ws + 11714560);
  ushort_t* w3l    = (ushort_t*)(ws + 11780096);

  hipMemsetAsync(ws + 9469952, 0, 2097152 + 16384, stream);

  k_front <<<705,  256, 0, stream>>>(e4w, e4b, e4wP, e2w, w2h, w2l, e3w, w3h, w3l,
                                     x, p1w, p1b, p2w, p2b, h_node, ei, cnt);
  k_mlp   <<<256,  512, 0, stream>>>(ea, e1w, e1b, w2h, w2l, e2b,
                                     w3h, w3l, e3b, e3Tf);
  k_gemm  <<<256,  512, 0, stream>>>(h_node, ei, e3Tf, e4wP, agg);
  k_pool  <<<64,   128, 0, stream>>>(agg, cnt, bat, (float*)d_out);
}